// Round 4
// baseline (202.441 us; speedup 1.0000x reference)
//
#include <hip/hip_runtime.h>

#define MAX_SEQ   2048
#define LAT_SEQ   1024
#define DIM       1024
#define DLAT      5
#define K_CB      4375
#define ZERO_IDX  2187   // (0+3)*625 + (0+2)*125 + (0+2)*25 + (0+2)*5 + (0+2)

// ws layout: used[0..4374], counter = used[4375], WencT at float offset 8192.

// ---------------------------------------------------------------------------
// K0: init usage bitmap (+ always-used all-zero code), zero the arrival
// counter, and build WencT[5][1024] so encode reads are float4-coalesced.
__global__ void prep(const float* __restrict__ Wenc,
                     float* __restrict__ WencT,
                     int* __restrict__ used) {
    int i = blockIdx.x * blockDim.x + threadIdx.x;      // 0..5119
    if (i < 5120) {
        int e = i >> 10, d = i & 1023;
        WencT[i] = Wenc[d * DLAT + e];
    }
    if (i <= K_CB) used[i] = (i == ZERO_IDX) ? 1 : 0;   // i==K_CB zeroes counter
}

// ---------------------------------------------------------------------------
// K1: fused encode -> quantize -> decode, one wave per (unmasked, masked)
// token pair; last block reduces the usage bitmap and writes the scalars.
__global__ __launch_bounds__(256) void fsq_main(
    const float* __restrict__ x,
    const float* __restrict__ WencT,  // [5][1024]
    const float* __restrict__ Wdec,   // [5][1024]
    float* __restrict__ xout,         // [32768][1024]
    float* __restrict__ ze,           // [32768][5]
    float* __restrict__ zq,           // [32768][5]
    int*   __restrict__ used,         // [4375] + counter at [4375]
    float* __restrict__ scal)         // 3 scalars
{
    const int wave = threadIdx.x >> 6;
    const int lane = threadIdx.x & 63;
    const int u    = blockIdx.x * 4 + wave;          // unmasked ordinal 0..16383
    const int b    = u >> 10;
    const int s    = u & 1023;
    const int t    = b * MAX_SEQ + s;                // unmasked token
    const int tm   = t + LAT_SEQ;                    // masked partner
    const long long row  = (long long)t  * DIM;
    const long long rowm = (long long)tm * DIM;

    // ---- issue x loads for the unmasked token
    float4 v[4];
    #pragma unroll
    for (int q = 0; q < 4; ++q)
        v[q] = *(const float4*)(x + row + q * 256 + lane * 4);

    // ---- masked partner: independent zero-store work hides encode latency
    {
        const float4 z4 = make_float4(0.f, 0.f, 0.f, 0.f);
        #pragma unroll
        for (int q = 0; q < 4; ++q)
            *(float4*)(xout + rowm + q * 256 + lane * 4) = z4;
        if (lane < DLAT) {
            ze[tm * DLAT + lane] = 0.f;
            zq[tm * DLAT + lane] = 0.f;
        }
    }

    // ---- encode: h[e] = sum_d x[t,d] * Wenc[d,e]
    float acc[DLAT] = {0.f, 0.f, 0.f, 0.f, 0.f};
    #pragma unroll
    for (int q = 0; q < 4; ++q) {
        const int c0 = q * 256 + lane * 4;
        #pragma unroll
        for (int e = 0; e < DLAT; ++e) {
            const float4 w = *(const float4*)(WencT + e * DIM + c0);
            acc[e] += v[q].x * w.x + v[q].y * w.y + v[q].z * w.z + v[q].w * w.w;
        }
    }
    #pragma unroll
    for (int e = 0; e < DLAT; ++e) {
        float a = acc[e];
        #pragma unroll
        for (int o = 32; o > 0; o >>= 1) a += __shfl_xor(a, o, 64);
        acc[e] = a;
    }

    // ---- quantize: z_q = rint(half * tanh(h))  (rint = half-to-even)
    const float halfv[DLAT] = {3.f, 2.f, 2.f, 2.f, 2.f};
    float zqv[DLAT];
    int   ci[DLAT];
    #pragma unroll
    for (int e = 0; e < DLAT; ++e) {
        const float zsq = halfv[e] * tanhf(acc[e]);
        zqv[e] = rintf(zsq);
        ci[e]  = (int)zqv[e];
    }

    if (lane < DLAT) {
        ze[t * DLAT + lane] = acc[lane];
        zq[t * DLAT + lane] = zqv[lane];
    }
    if (lane == 0) {
        const int idx = ((((ci[0] + 3) * 5 + (ci[1] + 2)) * 5 + (ci[2] + 2)) * 5
                          + (ci[3] + 2)) * 5 + (ci[4] + 2);
        used[idx] = 1;   // benign race: everyone stores 1
    }

    // ---- decode: x_out[t,d] = sum_e z_q[e] * Wdec[e,d]
    #pragma unroll
    for (int q = 0; q < 4; ++q) {
        const int c0 = q * 256 + lane * 4;
        float4 o = make_float4(0.f, 0.f, 0.f, 0.f);
        #pragma unroll
        for (int e = 0; e < DLAT; ++e) {
            const float4 w = *(const float4*)(Wdec + e * DIM + c0);
            o.x += zqv[e] * w.x; o.y += zqv[e] * w.y;
            o.z += zqv[e] * w.z; o.w += zqv[e] * w.w;
        }
        *(float4*)(xout + row + c0) = o;
    }

    // ---- last block computes the scalars
    __shared__ int sh[256];
    __shared__ int is_last;
    __syncthreads();
    if (threadIdx.x == 0) {
        __threadfence();                               // release our stores
        int* counter = used + K_CB;
        is_last = (atomicAdd(counter, 1) == (int)gridDim.x - 1);
    }
    __syncthreads();
    if (is_last) {
        __threadfence();                               // acquire others' stores
        const int tt = threadIdx.x;
        int sum = 0;
        const volatile int* uv = used;
        for (int i = tt; i < K_CB; i += 256) sum += uv[i];
        sh[tt] = sum;
        __syncthreads();
        for (int o = 128; o > 0; o >>= 1) {
            if (tt < o) sh[tt] += sh[tt + o];
            __syncthreads();
        }
        if (tt == 0) {
            const float uniq  = (float)sh[0];
            const float usage = (uniq + ((float)K_CB - uniq) * expf(-1.0f)) / (float)K_CB;
            scal[0] = usage;          // output 3: usage
            scal[1] = uniq;           // output 4: unique (stored as its value)
            scal[2] = 0.0f;           // output 5: percent_masked
        }
    }
}

// ---------------------------------------------------------------------------
extern "C" void kernel_launch(void* const* d_in, const int* in_sizes, int n_in,
                              void* d_out, int out_size, void* d_ws, size_t ws_size,
                              hipStream_t stream) {
    const float* x    = (const float*)d_in[0];   // [16,2048,1024]
    const float* Wenc = (const float*)d_in[1];   // [1024,5]
    const float* Wdec = (const float*)d_in[2];   // [5,1024]

    float* out  = (float*)d_out;
    float* xout = out;                                  // 33554432
    float* ze   = out + 33554432;                       // 163840
    float* zq   = ze + 163840;                          // 163840
    float* scal = zq + 163840;                          // 3 scalars

    int*   used  = (int*)d_ws;                          // 4375 flags + counter
    float* WencT = (float*)d_ws + 8192;                 // [5][1024], 20 KB

    prep<<<20, 256, 0, stream>>>(Wenc, WencT, used);
    fsq_main<<<4096, 256, 0, stream>>>(x, WencT, Wdec, xout, ze, zq, used, scal);
}

// Round 5
// 46.948 us; speedup vs baseline: 4.3120x; 4.3120x over previous
//
#include <hip/hip_runtime.h>

#define MAX_SEQ   2048
#define LAT_SEQ   1024
#define DIM       1024
#define DLAT      5
#define K_CB      4375
#define ZERO_IDX  2187   // (0+3)*625 + (0+2)*125 + (0+2)*25 + (0+2)*5 + (0+2)

// ws layout: used[0..4374], WencT at float offset 8192.

// ---------------------------------------------------------------------------
// K0: init usage bitmap (+ always-used all-zero code) and build
// WencT[5][1024] so encode reads are float4-coalesced.
__global__ void prep(const float* __restrict__ Wenc,
                     float* __restrict__ WencT,
                     int* __restrict__ used) {
    int i = blockIdx.x * blockDim.x + threadIdx.x;      // 0..5119
    if (i < 5120) {
        int e = i >> 10, d = i & 1023;
        WencT[i] = Wenc[d * DLAT + e];
    }
    if (i < K_CB) used[i] = (i == ZERO_IDX) ? 1 : 0;
}

// ---------------------------------------------------------------------------
// K1: fused encode -> quantize -> decode, one wave per (unmasked, masked)
// token pair. No fences, no atomics — scalars are done by a separate kernel.
__global__ __launch_bounds__(256) void fsq_main(
    const float* __restrict__ x,
    const float* __restrict__ WencT,  // [5][1024]
    const float* __restrict__ Wdec,   // [5][1024]
    float* __restrict__ xout,         // [32768][1024]
    float* __restrict__ ze,           // [32768][5]
    float* __restrict__ zq,           // [32768][5]
    int*   __restrict__ used)         // [4375]
{
    const int wave = threadIdx.x >> 6;
    const int lane = threadIdx.x & 63;
    const int u    = blockIdx.x * 4 + wave;          // unmasked ordinal 0..16383
    const int b    = u >> 10;
    const int s    = u & 1023;
    const int t    = b * MAX_SEQ + s;                // unmasked token
    const int tm   = t + LAT_SEQ;                    // masked partner
    const long long row  = (long long)t  * DIM;
    const long long rowm = (long long)tm * DIM;

    // ---- issue x loads for the unmasked token
    float4 v[4];
    #pragma unroll
    for (int q = 0; q < 4; ++q)
        v[q] = *(const float4*)(x + row + q * 256 + lane * 4);

    // ---- masked partner: independent zero-store work hides encode latency
    {
        const float4 z4 = make_float4(0.f, 0.f, 0.f, 0.f);
        #pragma unroll
        for (int q = 0; q < 4; ++q)
            *(float4*)(xout + rowm + q * 256 + lane * 4) = z4;
        if (lane < DLAT) {
            ze[tm * DLAT + lane] = 0.f;
            zq[tm * DLAT + lane] = 0.f;
        }
    }

    // ---- encode: h[e] = sum_d x[t,d] * Wenc[d,e]
    float acc[DLAT] = {0.f, 0.f, 0.f, 0.f, 0.f};
    #pragma unroll
    for (int q = 0; q < 4; ++q) {
        const int c0 = q * 256 + lane * 4;
        #pragma unroll
        for (int e = 0; e < DLAT; ++e) {
            const float4 w = *(const float4*)(WencT + e * DIM + c0);
            acc[e] += v[q].x * w.x + v[q].y * w.y + v[q].z * w.z + v[q].w * w.w;
        }
    }
    #pragma unroll
    for (int e = 0; e < DLAT; ++e) {
        float a = acc[e];
        #pragma unroll
        for (int o = 32; o > 0; o >>= 1) a += __shfl_xor(a, o, 64);
        acc[e] = a;
    }

    // ---- quantize: z_q = rint(half * tanh(h))  (rint = half-to-even)
    const float halfv[DLAT] = {3.f, 2.f, 2.f, 2.f, 2.f};
    float zqv[DLAT];
    int   ci[DLAT];
    #pragma unroll
    for (int e = 0; e < DLAT; ++e) {
        const float zsq = halfv[e] * tanhf(acc[e]);
        zqv[e] = rintf(zsq);
        ci[e]  = (int)zqv[e];
    }

    if (lane < DLAT) {
        ze[t * DLAT + lane] = acc[lane];
        zq[t * DLAT + lane] = zqv[lane];
    }
    if (lane == 0) {
        const int idx = ((((ci[0] + 3) * 5 + (ci[1] + 2)) * 5 + (ci[2] + 2)) * 5
                          + (ci[3] + 2)) * 5 + (ci[4] + 2);
        used[idx] = 1;   // benign race: everyone stores 1
    }

    // ---- decode: x_out[t,d] = sum_e z_q[e] * Wdec[e,d]
    #pragma unroll
    for (int q = 0; q < 4; ++q) {
        const int c0 = q * 256 + lane * 4;
        float4 o = make_float4(0.f, 0.f, 0.f, 0.f);
        #pragma unroll
        for (int e = 0; e < DLAT; ++e) {
            const float4 w = *(const float4*)(Wdec + e * DIM + c0);
            o.x += zqv[e] * w.x; o.y += zqv[e] * w.y;
            o.z += zqv[e] * w.z; o.w += zqv[e] * w.w;
        }
        *(float4*)(xout + row + c0) = o;
    }
}

// ---------------------------------------------------------------------------
// K2: reduce usage flags -> unique; write the three scalar outputs.
__global__ void finalize(const int* __restrict__ used, float* __restrict__ scal) {
    __shared__ int sh[256];
    const int t = threadIdx.x;
    int sum = 0;
    for (int i = t; i < K_CB; i += 256) sum += used[i];
    sh[t] = sum;
    __syncthreads();
    for (int o = 128; o > 0; o >>= 1) {
        if (t < o) sh[t] += sh[t + o];
        __syncthreads();
    }
    if (t == 0) {
        const float uniq  = (float)sh[0];
        const float usage = (uniq + ((float)K_CB - uniq) * expf(-1.0f)) / (float)K_CB;
        scal[0] = usage;          // output 3: usage
        scal[1] = uniq;           // output 4: unique (stored as its value)
        scal[2] = 0.0f;           // output 5: percent_masked
    }
}

// ---------------------------------------------------------------------------
extern "C" void kernel_launch(void* const* d_in, const int* in_sizes, int n_in,
                              void* d_out, int out_size, void* d_ws, size_t ws_size,
                              hipStream_t stream) {
    const float* x    = (const float*)d_in[0];   // [16,2048,1024]
    const float* Wenc = (const float*)d_in[1];   // [1024,5]
    const float* Wdec = (const float*)d_in[2];   // [5,1024]

    float* out  = (float*)d_out;
    float* xout = out;                                  // 33554432
    float* ze   = out + 33554432;                       // 163840
    float* zq   = ze + 163840;                          // 163840
    float* scal = zq + 163840;                          // 3 scalars

    int*   used  = (int*)d_ws;                          // 4375 flags
    float* WencT = (float*)d_ws + 8192;                 // [5][1024], 20 KB

    prep<<<20, 256, 0, stream>>>(Wenc, WencT, used);
    fsq_main<<<4096, 256, 0, stream>>>(x, WencT, Wdec, xout, ze, zq, used);
    finalize<<<1, 256, 0, stream>>>(used, scal);
}

// Round 6
// 44.903 us; speedup vs baseline: 4.5084x; 1.0456x over previous
//
#include <hip/hip_runtime.h>

#define MAX_SEQ   2048
#define LAT_SEQ   1024
#define DIM       1024
#define DLAT      5
#define K_CB      4375
#define ZERO_IDX  2187   // (0+3)*625 + (0+2)*125 + (0+2)*25 + (0+2)*5 + (0+2)

// ---------------------------------------------------------------------------
// Fused encode -> quantize -> decode. One wave per 2 (unmasked, masked) token
// pairs. Weights staged in LDS per block (Wenc transposed in-block).
__global__ __launch_bounds__(256) void fsq_main(
    const float* __restrict__ x,
    const float* __restrict__ Wenc,   // [1024][5]
    const float* __restrict__ Wdec,   // [5][1024]
    float* __restrict__ xout,         // [32768][1024]
    float* __restrict__ ze,           // [32768][5]
    float* __restrict__ zq,           // [32768][5]
    int*   __restrict__ used)         // [4375], pre-zeroed via memset
{
    __shared__ float wencT[DLAT * DIM];   // [5][1024]
    __shared__ float wdecS[DLAT * DIM];   // [5][1024]

    const int tid  = threadIdx.x;
    const int wave = tid >> 6;
    const int lane = tid & 63;
    const int u0   = (blockIdx.x * 4 + wave) * 2;    // unmasked ordinal base

    int t[2];  long long row[2], rowm[2];
    #pragma unroll
    for (int p = 0; p < 2; ++p) {
        const int u = u0 + p;
        const int b = u >> 10, s = u & 1023;
        t[p]    = b * MAX_SEQ + s;                    // unmasked token
        row[p]  = (long long)t[p] * DIM;
        rowm[p] = row[p] + (long long)LAT_SEQ * DIM;  // masked partner row
    }

    // ---- issue x loads early (8 float4 in flight)
    float4 v[2][4];
    #pragma unroll
    for (int p = 0; p < 2; ++p)
        #pragma unroll
        for (int q = 0; q < 4; ++q)
            v[p][q] = *(const float4*)(x + row[p] + q * 256 + lane * 4);

    // ---- masked partners: independent zero-store work
    const float4 z4 = make_float4(0.f, 0.f, 0.f, 0.f);
    #pragma unroll
    for (int p = 0; p < 2; ++p) {
        #pragma unroll
        for (int q = 0; q < 4; ++q)
            *(float4*)(xout + rowm[p] + q * 256 + lane * 4) = z4;
        if (lane < DLAT) {
            const int tm = t[p] + LAT_SEQ;
            ze[tm * DLAT + lane] = 0.f;
            zq[tm * DLAT + lane] = 0.f;
        }
    }

    // ---- cooperative weight staging into LDS
    {
        const float4* src = (const float4*)Wdec;      // [5][1024] already coalesced
        float4*       dst = (float4*)wdecS;
        #pragma unroll
        for (int m = 0; m < 5; ++m)
            dst[tid + 256 * m] = src[tid + 256 * m];
        #pragma unroll
        for (int m = 0; m < 20; ++m) {                // WencT[e][d] = Wenc[d][e]
            const int k = tid + 256 * m;
            const int e = k >> 10, d = k & 1023;
            wencT[k] = Wenc[d * DLAT + e];
        }
    }
    __syncthreads();

    // ---- encode: h[p][e] = sum_d x[t_p,d] * Wenc[d,e]
    float acc[2][DLAT] = {};
    #pragma unroll
    for (int q = 0; q < 4; ++q) {
        const int c0 = q * 256 + lane * 4;
        #pragma unroll
        for (int e = 0; e < DLAT; ++e) {
            const float4 w = *(const float4*)(wencT + e * DIM + c0);
            #pragma unroll
            for (int p = 0; p < 2; ++p)
                acc[p][e] += v[p][q].x * w.x + v[p][q].y * w.y
                           + v[p][q].z * w.z + v[p][q].w * w.w;
        }
    }
    #pragma unroll
    for (int p = 0; p < 2; ++p)
        #pragma unroll
        for (int e = 0; e < DLAT; ++e) {
            float a = acc[p][e];
            #pragma unroll
            for (int o = 32; o > 0; o >>= 1) a += __shfl_xor(a, o, 64);
            acc[p][e] = a;
        }

    // ---- quantize: z_q = rint(half * tanh(h))  (rint = half-to-even)
    const float halfv[DLAT] = {3.f, 2.f, 2.f, 2.f, 2.f};
    float zqv[2][DLAT];
    #pragma unroll
    for (int p = 0; p < 2; ++p) {
        int ci[DLAT];
        #pragma unroll
        for (int e = 0; e < DLAT; ++e) {
            const float zsq = halfv[e] * tanhf(acc[p][e]);
            zqv[p][e] = rintf(zsq);
            ci[e]     = (int)zqv[p][e];
        }
        if (lane < DLAT) {
            ze[t[p] * DLAT + lane] = acc[p][lane];
            zq[t[p] * DLAT + lane] = zqv[p][lane];
        }
        if (lane == 0) {
            const int idx = ((((ci[0] + 3) * 5 + (ci[1] + 2)) * 5 + (ci[2] + 2)) * 5
                              + (ci[3] + 2)) * 5 + (ci[4] + 2);
            used[idx] = 1;   // benign race: everyone stores 1
        }
    }

    // ---- decode: x_out[t,d] = sum_e z_q[e] * Wdec[e,d]
    #pragma unroll
    for (int q = 0; q < 4; ++q) {
        const int c0 = q * 256 + lane * 4;
        float4 o[2] = {make_float4(0.f,0.f,0.f,0.f), make_float4(0.f,0.f,0.f,0.f)};
        #pragma unroll
        for (int e = 0; e < DLAT; ++e) {
            const float4 w = *(const float4*)(wdecS + e * DIM + c0);
            #pragma unroll
            for (int p = 0; p < 2; ++p) {
                o[p].x += zqv[p][e] * w.x; o[p].y += zqv[p][e] * w.y;
                o[p].z += zqv[p][e] * w.z; o[p].w += zqv[p][e] * w.w;
            }
        }
        #pragma unroll
        for (int p = 0; p < 2; ++p)
            *(float4*)(xout + row[p] + c0) = o[p];
    }
}

// ---------------------------------------------------------------------------
// Reduce usage flags -> unique; zero code is always used (masked tokens) even
// though no wave marks it.
__global__ void finalize(const int* __restrict__ used, float* __restrict__ scal) {
    __shared__ int sh[256];
    const int t = threadIdx.x;
    int sum = 0;
    for (int i = t; i < K_CB; i += 256) sum += used[i];
    sh[t] = sum;
    __syncthreads();
    for (int o = 128; o > 0; o >>= 1) {
        if (t < o) sh[t] += sh[t + o];
        __syncthreads();
    }
    if (t == 0) {
        const float uniq  = (float)sh[0] + (used[ZERO_IDX] ? 0.f : 1.f);
        const float usage = (uniq + ((float)K_CB - uniq) * expf(-1.0f)) / (float)K_CB;
        scal[0] = usage;          // output 3: usage
        scal[1] = uniq;           // output 4: unique (stored as its value)
        scal[2] = 0.0f;           // output 5: percent_masked
    }
}

// ---------------------------------------------------------------------------
extern "C" void kernel_launch(void* const* d_in, const int* in_sizes, int n_in,
                              void* d_out, int out_size, void* d_ws, size_t ws_size,
                              hipStream_t stream) {
    const float* x    = (const float*)d_in[0];   // [16,2048,1024]
    const float* Wenc = (const float*)d_in[1];   // [1024,5]
    const float* Wdec = (const float*)d_in[2];   // [5,1024]

    float* out  = (float*)d_out;
    float* xout = out;                                  // 33554432
    float* ze   = out + 33554432;                       // 163840
    float* zq   = ze + 163840;                          // 163840
    float* scal = zq + 163840;                          // 3 scalars

    int* used = (int*)d_ws;                             // 4375 flags

    hipMemsetAsync(used, 0, K_CB * sizeof(int), stream);
    fsq_main<<<2048, 256, 0, stream>>>(x, Wenc, Wdec, xout, ze, zq, used);
    finalize<<<1, 256, 0, stream>>>(used, scal);
}